// Round 12
// baseline (166.711 us; speedup 1.0000x reference)
//
#include <hip/hip_runtime.h>

// NRC fused encode + 7-layer W=64 MLP. R12 = R11 (K=32 register chaining,
// tau-permuted weights) + WEIGHTS IN LDS (shared per block).
//
// R11 post-mortem: freeing LDS didn't move occupancy (26.5%) -> waves are
// latency-bound, not resource-bound. Hidden cost: every wave re-read 51.2KB
// of packed weights from L2 (16384 waves x 51.2KB = 819MB = ~24us of L2 at
// 34.5TB/s, in 7 dependent batches/wave under contention). R12: each block
// (4 waves) copies the weight image to LDS once (coalesced, overlapped with
// encode, single __syncthreads), layers read ds_read_b128 (2-way bank
// aliasing = free). Global weight traffic 819->210MB; L2 contention gone.
// LDS: 51200 (weights) + 4 waves x 2048 (1-tile staging, 4 passes) = 59392B.
//
// 16x16x32 f16 fragment maps (verified):
//   A[m=lane&15][k=(lane>>4)*8+j], B[k=(lane>>4)*8+j][n=lane&15],
//   D[row=(lane>>4)*4+r][col=lane&15]  (4 blocks mt: row=mt*16+q*4+r)
// Chaining: bf[kt]=concat(relu(pack(acc[2kt])), relu(pack(acc[2kt+1])));
// k-index mismatch absorbed by permuting W1..W5,W6 columns with
// tau(x)=32(x>>5)+16((x&7)>>2)+4((x>>3)&3)+(x&3) at pack time.

typedef _Float16 f16;
typedef f16 f16x2 __attribute__((ext_vector_type(2)));
typedef f16 f16x4 __attribute__((ext_vector_type(4)));
typedef f16 f16x8 __attribute__((ext_vector_type(8)));
typedef float f32x4 __attribute__((ext_vector_type(4)));

#define MFMA32(A, B, C) __builtin_amdgcn_mfma_f32_16x16x32_f16(A, B, C, 0, 0, 0)
#define LDS_FENCE() __asm__ volatile("" ::: "memory")

static constexpr int TILES = 4;       // 16-sample tiles per wave
static constexpr int WAVES = 4;       // waves per block
static constexpr int BLOCK = WAVES * 64;   // 256
static constexpr int SPB   = WAVES * 64;   // 256 samples per block

static constexpr int    WUNITS   = 50;     // 48 hidden frag-units + 2 W6
static constexpr int    WCHUNKS  = WUNITS * 64;          // 3200 x 16B
static constexpr size_t WS_BYTES = (size_t)WCHUNKS * 16; // 51200
static constexpr int    LDS_W    = 51200;                // weight region bytes

__host__ __device__ __forceinline__ int tau(int x) {
    return (x & 32) + ((x & 7) >> 2) * 16 + ((x >> 3) & 3) * 4 + (x & 3);
}

__device__ __forceinline__ f16x2 pkh(float a, float b) {
    return __builtin_bit_cast(f16x2, __builtin_amdgcn_cvt_pkrtz(a, b));
}

__device__ __forceinline__ f16x8 pack8(const float* f) {
    f16x2 a = pkh(f[0], f[1]);
    f16x2 b = pkh(f[2], f[3]);
    f16x2 c = pkh(f[4], f[5]);
    f16x2 d = pkh(f[6], f[7]);
    f16x8 v;
    v[0] = a[0]; v[1] = a[1]; v[2] = b[0]; v[3] = b[1];
    v[4] = c[0]; v[5] = c[1]; v[6] = d[0]; v[7] = d[1];
    return v;
}

__device__ __forceinline__ f16x4 pack4(f32x4 v) {
    f16x2 a = pkh(v[0], v[1]);
    f16x2 b = pkh(v[2], v[3]);
    f16x4 r;
    r[0] = a[0]; r[1] = a[1]; r[2] = b[0]; r[3] = b[1];
    return r;
}

// atan2(y,x) / (2*pi)
__device__ __forceinline__ float fast_atan2_rev(float y, float x) {
    const float ax = __builtin_fabsf(x), ay = __builtin_fabsf(y);
    const float mx = fmaxf(ax, ay), mn = fminf(ax, ay);
    const float a = mn * __builtin_amdgcn_rcpf(fmaxf(mx, 1e-30f));
    const float s = a * a;
    float r = a * (0.99997726f + s * (-0.33262347f + s * (0.19354346f +
              s * (-0.11643287f + s * (0.05265332f - s * 0.01172120f)))));
    if (ay > ax) r = 1.5707963268f - r;
    if (x < 0.0f) r = 3.1415926536f - r;
    r = (y < 0.0f) ? -r : r;
    return r * 0.15915494309189535f;
}

// acos(x), |err| <= 6.8e-5 rad
__device__ __forceinline__ float fast_acos(float x) {
    const float ax = __builtin_fabsf(x);
    const float t = __builtin_amdgcn_sqrtf(1.0f - ax);
    const float p = t * (1.5707288f + ax * (-0.2121144f +
                    ax * (0.0742610f - ax * 0.0187293f)));
    return (x < 0.0f) ? (3.1415926536f - p) : p;
}

// one-blob: out[i]=exp(-8(x-c_i)^2) via exp ladder (2 transcendentals)
__device__ __forceinline__ void blob4(float x, float* out) {
    const float dx = x - 0.125f;
    const float E0 = __expf(-8.0f * dx * dx);
    const float R  = __expf(4.0f * dx);
    const float t1 = R * 0.60653066f;
    const float t2 = R * 0.22313016f;
    const float t3 = R * 0.082084999f;
    out[0] = E0;
    out[1] = E0 * t1;
    out[2] = out[1] * t2;
    out[3] = out[2] * t3;
}

// compute packed-weight chunk c (= unit*64 + lane2) from the f32 weights
__device__ __forceinline__ f16x8 make_wchunk(
    int c, const float* __restrict__ W0, const float* __restrict__ W1,
    const float* __restrict__ W2, const float* __restrict__ W3,
    const float* __restrict__ W4, const float* __restrict__ W5,
    const float* __restrict__ W6)
{
    const int lane2 = c & 63;
    const int unit  = c >> 6;
    const int q = lane2 >> 4, m = lane2 & 15;
    f16x8 v;
    if (unit < 48) {
        const int l = unit >> 3, kt = (unit & 7) >> 2, mt = unit & 3;
        const float* Ws[6] = {W0, W1, W2, W3, W4, W5};
        const float* __restrict__ Wl = Ws[l];
#pragma unroll
        for (int j = 0; j < 8; ++j) {
            const int x = kt * 32 + q * 8 + j;
            const int src = (l == 0) ? x : tau(x);
            v[j] = (f16)Wl[(mt * 16 + m) * 64 + src];
        }
    } else {
        const int kt = unit - 48;
#pragma unroll
        for (int j = 0; j < 8; ++j) {
            const int src = tau(kt * 32 + q * 8 + j);
            v[j] = (m < 3) ? (f16)W6[m * 64 + src] : (f16)0.0f;
        }
    }
    return v;
}

__global__ __launch_bounds__(256, 1) void pack_weights_kernel(
    const float* __restrict__ W0, const float* __restrict__ W1,
    const float* __restrict__ W2, const float* __restrict__ W3,
    const float* __restrict__ W4, const float* __restrict__ W5,
    const float* __restrict__ W6, f16* __restrict__ ws)
{
    const int c = (int)blockIdx.x * 256 + threadIdx.x;
    if (c >= WCHUNKS) return;
    *(f16x8*)(ws + (size_t)c * 8) = make_wchunk(c, W0, W1, W2, W3, W4, W5, W6);
}

__device__ __forceinline__ f16x8 cat44(f16x4 a, f16x4 b) {
    return __builtin_shufflevector(a, b, 0, 1, 2, 3, 4, 5, 6, 7);
}

template<int PACKED>
__global__ __launch_bounds__(BLOCK, 2) void nrc_mlp_kernel(
    const float* __restrict__ P,  const float* __restrict__ WI,
    const float* __restrict__ NV, const float* __restrict__ AL,
    const float* __restrict__ BE, const float* __restrict__ RR,
    const f16*   __restrict__ ws,
    const float* __restrict__ W0, const float* __restrict__ W1,
    const float* __restrict__ W2, const float* __restrict__ W3,
    const float* __restrict__ W4, const float* __restrict__ W5,
    const float* __restrict__ W6, float* __restrict__ Out)
{
    // LDS: [0, 51200) weight image | per-wave 2048B staging (1 tile) -> 59392B
    __shared__ __attribute__((aligned(16))) unsigned char smem[LDS_W + WAVES * 2048];

    const int tid  = threadIdx.x;
    const int lane = tid & 63;
    const int w    = tid >> 6;
    const int q    = lane >> 4;
    const int m    = lane & 15;
    unsigned char* const wlds = smem;
    unsigned char* const hb   = smem + LDS_W + w * 2048;

    const int wave_base = (int)blockIdx.x * SPB + w * 64;

    // ---- stage weight image into LDS (coalesced; overlaps encode below) ----
#pragma unroll
    for (int i = 0; i < (WCHUNKS + BLOCK - 1) / BLOCK; ++i) {
        const int c = i * BLOCK + tid;
        if (c < WCHUNKS) {
            f16x8 v;
            if (PACKED) v = *(const f16x8*)(ws + (size_t)c * 8);
            else        v = make_wchunk(c, W0, W1, W2, W3, W4, W5, W6);
            *(f16x8*)(wlds + c * 16) = v;
        }
    }

    float feat[64];
    float ab0, ab1, ab2;   // alpha+beta, delivered to epilogue via __shfl

    // ---- encode: one sample per lane (features stay in registers) ----
    {
        const int s = wave_base + lane;

        float pv[3], wv[3], nv[3], av[3], bv[3];
#pragma unroll
        for (int d = 0; d < 3; ++d) {
            pv[d] = P [s * 3 + d];
            wv[d] = WI[s * 3 + d];
            nv[d] = NV[s * 3 + d];
            av[d] = AL[s * 3 + d];
            bv[d] = BE[s * 3 + d];
        }
        const float rv = RR[s];

        // freq embed: base sin/cos at pi*p (revolutions) + exact angle doubling
#pragma unroll
        for (int d = 0; d < 3; ++d) {
            const float fr = __builtin_amdgcn_fractf(pv[d] * 0.5f);
            float sv = __builtin_amdgcn_sinf(fr);
            float cv = __builtin_amdgcn_cosf(fr);
            feat[d * 12 + 0] = sv;
            feat[d * 12 + 6] = cv;
#pragma unroll
            for (int k = 1; k < 6; ++k) {
                const float s2 = sv * sv;
                const float sc = sv * cv;
                cv = fmaf(-2.0f, s2, 1.0f);
                sv = sc + sc;
                feat[d * 12 + k]     = sv;
                feat[d * 12 + 6 + k] = cv;
            }
        }
#pragma unroll
        for (int which = 0; which < 2; ++which) {
            const float* dv = (which == 0) ? wv : nv;
            const int fo = 36 + which * 8;
            const float nr = __builtin_amdgcn_sqrtf(dv[0]*dv[0] + dv[1]*dv[1] + dv[2]*dv[2]) + 1e-8f;
            const float u  = fast_atan2_rev(dv[1], dv[0]) + 0.5f;
            float zc = dv[2] * __builtin_amdgcn_rcpf(nr);
            zc = fminf(fmaxf(zc, -1.0f + 1e-6f), 1.0f - 1e-6f);
            const float vv = fast_acos(zc) * 0.3183098861837907f;
            blob4(u,  &feat[fo]);
            blob4(vv, &feat[fo + 4]);
        }
        blob4(1.0f - __expf(-rv), &feat[52]);

        feat[56] = av[0]; feat[57] = av[1]; feat[58] = av[2];
        feat[59] = bv[0]; feat[60] = bv[1]; feat[61] = bv[2];
        feat[62] = 1.0f;  feat[63] = 1.0f;

        ab0 = av[0] + bv[0];
        ab1 = av[1] + bv[1];
        ab2 = av[2] + bv[2];
    }

    // ---- 4-pass feature staging through the 2KB/wave buffer ----
    // layout: [m][dword-slot], slot=(D+4m)&31, groups of 4 slots contiguous
    const int te = lane >> 4;
    f16x8 bf[TILES][2];
#pragma unroll
    for (int pass = 0; pass < TILES; ++pass) {
        if (te == pass) {
            unsigned char* const tb = hb + m * 128;
#pragma unroll
            for (int g = 0; g < 8; ++g) {
                const int slot0 = (4 * g + 4 * m) & 31;
                *(f16x8*)(tb + slot0 * 4) = pack8(&feat[g * 8]);
            }
        }
        LDS_FENCE();   // writes ordered before reads (same wave, HW in-order)
#pragma unroll
        for (int kt = 0; kt < 2; ++kt) {
            const int s0 = (16 * kt + 4 * q + 4 * m) & 31;
            bf[pass][kt] = *(const f16x8*)(hb + m * 128 + s0 * 4);
        }
        LDS_FENCE();   // reads ordered before next pass overwrites the buffer
    }

    __syncthreads();   // weight image complete before layer ds_reads

    const f16x4 zero4 = {(f16)0.0f, (f16)0.0f, (f16)0.0f, (f16)0.0f};
    unsigned char* const wb = wlds + lane * 16;

    // ---- hidden layers: pure-register chain, 8 MFMAs(16x16x32)/tile ----
#pragma unroll
    for (int layer = 0; layer < 6; ++layer) {
        f16x8 wa[8];   // frag index f = kt*4+mt
#pragma unroll
        for (int f = 0; f < 8; ++f)
            wa[f] = *(const f16x8*)(wb + (layer * 8 + f) * 1024);

#pragma unroll
        for (int t = 0; t < TILES; ++t) {
            f32x4 acc[4];
#pragma unroll
            for (int mt = 0; mt < 4; ++mt) {
                f32x4 z = {0.0f, 0.0f, 0.0f, 0.0f};
                z = MFMA32(wa[mt],     bf[t][0], z);
                z = MFMA32(wa[4 + mt], bf[t][1], z);
                acc[mt] = z;
            }
            f16x4 pk[4];
#pragma unroll
            for (int mt = 0; mt < 4; ++mt)
                pk[mt] = __builtin_elementwise_max(pack4(acc[mt]), zero4);
            bf[t][0] = cat44(pk[0], pk[1]);   // tau absorbed in next layer's cols
            bf[t][1] = cat44(pk[2], pk[3]);
        }
    }

    // ---- final layer (W6, tau-permuted cols) + scale by (alpha+beta) ----
    {
        const f16x8 w6f0 = *(const f16x8*)(wb + 48 * 1024);
        const f16x8 w6f1 = *(const f16x8*)(wb + 49 * 1024);
#pragma unroll
        for (int t = 0; t < TILES; ++t) {
            f32x4 z = {0.0f, 0.0f, 0.0f, 0.0f};
            z = MFMA32(w6f0, bf[t][0], z);
            z = MFMA32(w6f1, bf[t][1], z);
            // alpha+beta of sample t*16+m lives in lane t*16+m's registers
            const int src = t * 16 + m;
            const float s0 = __shfl(ab0, src);
            const float s1 = __shfl(ab1, src);
            const float s2 = __shfl(ab2, src);
            if (lane < 16) {   // q==0: D rows r=0..2 = output channels, col m
                const int s = wave_base + t * 16 + m;
                float* o = Out + s * 3;
                o[0] = z[0] * s0;
                o[1] = z[1] * s1;
                o[2] = z[2] * s2;
            }
        }
    }
}

extern "C" void kernel_launch(void* const* d_in, const int* in_sizes, int n_in,
                              void* d_out, int out_size, void* d_ws, size_t ws_size,
                              hipStream_t stream) {
    (void)n_in; (void)out_size;
    const float* P  = (const float*)d_in[0];
    const float* WI = (const float*)d_in[1];
    const float* NV = (const float*)d_in[2];
    const float* AL = (const float*)d_in[3];
    const float* BE = (const float*)d_in[4];
    const float* RR = (const float*)d_in[5];
    const float* W0 = (const float*)d_in[6];
    const float* W1 = (const float*)d_in[7];
    const float* W2 = (const float*)d_in[8];
    const float* W3 = (const float*)d_in[9];
    const float* W4 = (const float*)d_in[10];
    const float* W5 = (const float*)d_in[11];
    const float* W6 = (const float*)d_in[12];
    f16*   ws  = (f16*)d_ws;
    float* Out = (float*)d_out;

    const int Bn = in_sizes[0] / 3;     // 1,048,576
    const int grid = Bn / SPB;          // 4096 blocks of 256 threads

    // ws_size fixed per session -> same path every call (graph-safe).
    if (ws_size >= WS_BYTES) {
        hipLaunchKernelGGL(pack_weights_kernel, dim3((WCHUNKS + 255) / 256),
                           dim3(256), 0, stream, W0, W1, W2, W3, W4, W5, W6, ws);
        hipLaunchKernelGGL((nrc_mlp_kernel<1>), dim3(grid), dim3(BLOCK), 0, stream,
                           P, WI, NV, AL, BE, RR, ws,
                           W0, W1, W2, W3, W4, W5, W6, Out);
    } else {
        hipLaunchKernelGGL((nrc_mlp_kernel<0>), dim3(grid), dim3(BLOCK), 0, stream,
                           P, WI, NV, AL, BE, RR, ws,
                           W0, W1, W2, W3, W4, W5, W6, Out);
    }
}

// Round 13
// 154.337 us; speedup vs baseline: 1.0802x; 1.0802x over previous
//
#include <hip/hip_runtime.h>

// NRC fused encode + 7-layer W=64 MLP. R13 = R12 (weights in LDS, K=32
// register chaining, tau-permuted) with the LDS budget un-throttled:
//
// R12 post-mortem: weights-in-LDS made waves 21% more efficient per resident
// cycle (dur*residency 510 -> 403 wave-us) but 59.4KB LDS capped occupancy at
// 2 blocks/CU (18%) -> net regression. R13: feature staging and the weight
// image TIME-SHARE the same LDS region (staging happens before weights are
// needed): LDS = 51200B total. BLOCK=512 (8 waves, grid 2048 exact) ->
// 2 blocks/CU = 16 waves/CU cap, VGPR-capped not LDS-capped.
// Phases: encode(regs) -> per-wave staging in wave-private 2KB slice of the
// future weight region -> syncthreads -> cooperative weight stage ->
// syncthreads -> register-chained layers (ds_read_b128 weights, 2-way
// aliasing = free).
//
// 16x16x32 f16 fragment maps (verified):
//   A[m=lane&15][k=(lane>>4)*8+j], B[k=(lane>>4)*8+j][n=lane&15],
//   D[row=(lane>>4)*4+r][col=lane&15]  (4 blocks mt: row=mt*16+q*4+r)
// Chaining: bf[kt]=concat(relu(pack(acc[2kt])), relu(pack(acc[2kt+1])));
// k-index mismatch absorbed by permuting W1..W5,W6 columns with
// tau(x)=32(x>>5)+16((x&7)>>2)+4((x>>3)&3)+(x&3) at pack time.

typedef _Float16 f16;
typedef f16 f16x2 __attribute__((ext_vector_type(2)));
typedef f16 f16x4 __attribute__((ext_vector_type(4)));
typedef f16 f16x8 __attribute__((ext_vector_type(8)));
typedef float f32x4 __attribute__((ext_vector_type(4)));

#define MFMA32(A, B, C) __builtin_amdgcn_mfma_f32_16x16x32_f16(A, B, C, 0, 0, 0)
#define LDS_FENCE() __asm__ volatile("" ::: "memory")

static constexpr int TILES = 4;       // 16-sample tiles per wave
static constexpr int WAVES = 8;       // waves per block
static constexpr int BLOCK = WAVES * 64;   // 512
static constexpr int SPB   = WAVES * 64;   // 512 samples per block

static constexpr int    WUNITS   = 50;     // 48 hidden frag-units + 2 W6
static constexpr int    WCHUNKS  = WUNITS * 64;          // 3200 x 16B
static constexpr size_t WS_BYTES = (size_t)WCHUNKS * 16; // 51200
static constexpr int    LDS_W    = 51200;                // whole LDS region

__host__ __device__ __forceinline__ int tau(int x) {
    return (x & 32) + ((x & 7) >> 2) * 16 + ((x >> 3) & 3) * 4 + (x & 3);
}

__device__ __forceinline__ f16x2 pkh(float a, float b) {
    return __builtin_bit_cast(f16x2, __builtin_amdgcn_cvt_pkrtz(a, b));
}

__device__ __forceinline__ f16x8 pack8(const float* f) {
    f16x2 a = pkh(f[0], f[1]);
    f16x2 b = pkh(f[2], f[3]);
    f16x2 c = pkh(f[4], f[5]);
    f16x2 d = pkh(f[6], f[7]);
    f16x8 v;
    v[0] = a[0]; v[1] = a[1]; v[2] = b[0]; v[3] = b[1];
    v[4] = c[0]; v[5] = c[1]; v[6] = d[0]; v[7] = d[1];
    return v;
}

__device__ __forceinline__ f16x4 pack4(f32x4 v) {
    f16x2 a = pkh(v[0], v[1]);
    f16x2 b = pkh(v[2], v[3]);
    f16x4 r;
    r[0] = a[0]; r[1] = a[1]; r[2] = b[0]; r[3] = b[1];
    return r;
}

// atan2(y,x) / (2*pi)
__device__ __forceinline__ float fast_atan2_rev(float y, float x) {
    const float ax = __builtin_fabsf(x), ay = __builtin_fabsf(y);
    const float mx = fmaxf(ax, ay), mn = fminf(ax, ay);
    const float a = mn * __builtin_amdgcn_rcpf(fmaxf(mx, 1e-30f));
    const float s = a * a;
    float r = a * (0.99997726f + s * (-0.33262347f + s * (0.19354346f +
              s * (-0.11643287f + s * (0.05265332f - s * 0.01172120f)))));
    if (ay > ax) r = 1.5707963268f - r;
    if (x < 0.0f) r = 3.1415926536f - r;
    r = (y < 0.0f) ? -r : r;
    return r * 0.15915494309189535f;
}

// acos(x), |err| <= 6.8e-5 rad
__device__ __forceinline__ float fast_acos(float x) {
    const float ax = __builtin_fabsf(x);
    const float t = __builtin_amdgcn_sqrtf(1.0f - ax);
    const float p = t * (1.5707288f + ax * (-0.2121144f +
                    ax * (0.0742610f - ax * 0.0187293f)));
    return (x < 0.0f) ? (3.1415926536f - p) : p;
}

// one-blob: out[i]=exp(-8(x-c_i)^2) via exp ladder (2 transcendentals)
__device__ __forceinline__ void blob4(float x, float* out) {
    const float dx = x - 0.125f;
    const float E0 = __expf(-8.0f * dx * dx);
    const float R  = __expf(4.0f * dx);
    const float t1 = R * 0.60653066f;
    const float t2 = R * 0.22313016f;
    const float t3 = R * 0.082084999f;
    out[0] = E0;
    out[1] = E0 * t1;
    out[2] = out[1] * t2;
    out[3] = out[2] * t3;
}

// compute packed-weight chunk c (= unit*64 + lane2) from the f32 weights
__device__ __forceinline__ f16x8 make_wchunk(
    int c, const float* __restrict__ W0, const float* __restrict__ W1,
    const float* __restrict__ W2, const float* __restrict__ W3,
    const float* __restrict__ W4, const float* __restrict__ W5,
    const float* __restrict__ W6)
{
    const int lane2 = c & 63;
    const int unit  = c >> 6;
    const int q = lane2 >> 4, m = lane2 & 15;
    f16x8 v;
    if (unit < 48) {
        const int l = unit >> 3, kt = (unit & 7) >> 2, mt = unit & 3;
        const float* Ws[6] = {W0, W1, W2, W3, W4, W5};
        const float* __restrict__ Wl = Ws[l];
#pragma unroll
        for (int j = 0; j < 8; ++j) {
            const int x = kt * 32 + q * 8 + j;
            const int src = (l == 0) ? x : tau(x);
            v[j] = (f16)Wl[(mt * 16 + m) * 64 + src];
        }
    } else {
        const int kt = unit - 48;
#pragma unroll
        for (int j = 0; j < 8; ++j) {
            const int src = tau(kt * 32 + q * 8 + j);
            v[j] = (m < 3) ? (f16)W6[m * 64 + src] : (f16)0.0f;
        }
    }
    return v;
}

__global__ __launch_bounds__(256, 1) void pack_weights_kernel(
    const float* __restrict__ W0, const float* __restrict__ W1,
    const float* __restrict__ W2, const float* __restrict__ W3,
    const float* __restrict__ W4, const float* __restrict__ W5,
    const float* __restrict__ W6, f16* __restrict__ ws)
{
    const int c = (int)blockIdx.x * 256 + threadIdx.x;
    if (c >= WCHUNKS) return;
    *(f16x8*)(ws + (size_t)c * 8) = make_wchunk(c, W0, W1, W2, W3, W4, W5, W6);
}

__device__ __forceinline__ f16x8 cat44(f16x4 a, f16x4 b) {
    return __builtin_shufflevector(a, b, 0, 1, 2, 3, 4, 5, 6, 7);
}

template<int PACKED>
__global__ __launch_bounds__(BLOCK, 4) void nrc_mlp_kernel(
    const float* __restrict__ P,  const float* __restrict__ WI,
    const float* __restrict__ NV, const float* __restrict__ AL,
    const float* __restrict__ BE, const float* __restrict__ RR,
    const f16*   __restrict__ ws,
    const float* __restrict__ W0, const float* __restrict__ W1,
    const float* __restrict__ W2, const float* __restrict__ W3,
    const float* __restrict__ W4, const float* __restrict__ W5,
    const float* __restrict__ W6, float* __restrict__ Out)
{
    // ONE 51200B region: first used for per-wave feature staging (8 x 2048B
    // slices), then overwritten with the packed-weight image.
    __shared__ __attribute__((aligned(16))) unsigned char smem[LDS_W];

    const int tid  = threadIdx.x;
    const int lane = tid & 63;
    const int w    = tid >> 6;
    const int q    = lane >> 4;
    const int m    = lane & 15;
    unsigned char* const hb = smem + w * 2048;   // wave-private staging slice

    const int wave_base = (int)blockIdx.x * SPB + w * 64;

    float feat[64];
    float ab0, ab1, ab2;   // alpha+beta, delivered to epilogue via __shfl

    // ---- encode: one sample per lane (features stay in registers) ----
    {
        const int s = wave_base + lane;

        float pv[3], wv[3], nv[3], av[3], bv[3];
#pragma unroll
        for (int d = 0; d < 3; ++d) {
            pv[d] = P [s * 3 + d];
            wv[d] = WI[s * 3 + d];
            nv[d] = NV[s * 3 + d];
            av[d] = AL[s * 3 + d];
            bv[d] = BE[s * 3 + d];
        }
        const float rv = RR[s];

        // freq embed: base sin/cos at pi*p (revolutions) + exact angle doubling
#pragma unroll
        for (int d = 0; d < 3; ++d) {
            const float fr = __builtin_amdgcn_fractf(pv[d] * 0.5f);
            float sv = __builtin_amdgcn_sinf(fr);
            float cv = __builtin_amdgcn_cosf(fr);
            feat[d * 12 + 0] = sv;
            feat[d * 12 + 6] = cv;
#pragma unroll
            for (int k = 1; k < 6; ++k) {
                const float s2 = sv * sv;
                const float sc = sv * cv;
                cv = fmaf(-2.0f, s2, 1.0f);
                sv = sc + sc;
                feat[d * 12 + k]     = sv;
                feat[d * 12 + 6 + k] = cv;
            }
        }
#pragma unroll
        for (int which = 0; which < 2; ++which) {
            const float* dv = (which == 0) ? wv : nv;
            const int fo = 36 + which * 8;
            const float nr = __builtin_amdgcn_sqrtf(dv[0]*dv[0] + dv[1]*dv[1] + dv[2]*dv[2]) + 1e-8f;
            const float u  = fast_atan2_rev(dv[1], dv[0]) + 0.5f;
            float zc = dv[2] * __builtin_amdgcn_rcpf(nr);
            zc = fminf(fmaxf(zc, -1.0f + 1e-6f), 1.0f - 1e-6f);
            const float vv = fast_acos(zc) * 0.3183098861837907f;
            blob4(u,  &feat[fo]);
            blob4(vv, &feat[fo + 4]);
        }
        blob4(1.0f - __expf(-rv), &feat[52]);

        feat[56] = av[0]; feat[57] = av[1]; feat[58] = av[2];
        feat[59] = bv[0]; feat[60] = bv[1]; feat[61] = bv[2];
        feat[62] = 1.0f;  feat[63] = 1.0f;

        ab0 = av[0] + bv[0];
        ab1 = av[1] + bv[1];
        ab2 = av[2] + bv[2];
    }

    // ---- 4-pass feature staging through the wave-private 2KB slice ----
    // layout: [m][dword-slot], slot=(D+4m)&31, groups of 4 slots contiguous
    const int te = lane >> 4;
    f16x8 bf[TILES][2];
#pragma unroll
    for (int pass = 0; pass < TILES; ++pass) {
        if (te == pass) {
            unsigned char* const tb = hb + m * 128;
#pragma unroll
            for (int g = 0; g < 8; ++g) {
                const int slot0 = (4 * g + 4 * m) & 31;
                *(f16x8*)(tb + slot0 * 4) = pack8(&feat[g * 8]);
            }
        }
        LDS_FENCE();   // writes ordered before reads (same wave, HW in-order)
#pragma unroll
        for (int kt = 0; kt < 2; ++kt) {
            const int s0 = (16 * kt + 4 * q + 4 * m) & 31;
            bf[pass][kt] = *(const f16x8*)(hb + m * 128 + s0 * 4);
        }
        LDS_FENCE();   // reads ordered before next pass overwrites the buffer
    }

    __syncthreads();   // all staging reads done; region is free for weights

    // ---- cooperative weight-image stage into the SAME region ----
#pragma unroll
    for (int i = 0; i < (WCHUNKS + BLOCK - 1) / BLOCK; ++i) {
        const int c = i * BLOCK + tid;
        if (c < WCHUNKS) {
            f16x8 v;
            if (PACKED) v = *(const f16x8*)(ws + (size_t)c * 8);
            else        v = make_wchunk(c, W0, W1, W2, W3, W4, W5, W6);
            *(f16x8*)(smem + c * 16) = v;
        }
    }
    __syncthreads();   // weight image complete before layer ds_reads

    const f16x4 zero4 = {(f16)0.0f, (f16)0.0f, (f16)0.0f, (f16)0.0f};
    unsigned char* const wb = smem + lane * 16;

    // ---- hidden layers: pure-register chain, 8 MFMAs(16x16x32)/tile ----
#pragma unroll
    for (int layer = 0; layer < 6; ++layer) {
        f16x8 wa[8];   // frag index f = kt*4+mt
#pragma unroll
        for (int f = 0; f < 8; ++f)
            wa[f] = *(const f16x8*)(wb + (layer * 8 + f) * 1024);

#pragma unroll
        for (int t = 0; t < TILES; ++t) {
            f32x4 acc[4];
#pragma unroll
            for (int mt = 0; mt < 4; ++mt) {
                f32x4 z = {0.0f, 0.0f, 0.0f, 0.0f};
                z = MFMA32(wa[mt],     bf[t][0], z);
                z = MFMA32(wa[4 + mt], bf[t][1], z);
                acc[mt] = z;
            }
            f16x4 pk[4];
#pragma unroll
            for (int mt = 0; mt < 4; ++mt)
                pk[mt] = __builtin_elementwise_max(pack4(acc[mt]), zero4);
            bf[t][0] = cat44(pk[0], pk[1]);   // tau absorbed in next layer's cols
            bf[t][1] = cat44(pk[2], pk[3]);
        }
    }

    // ---- final layer (W6, tau-permuted cols) + scale by (alpha+beta) ----
    {
        const f16x8 w6f0 = *(const f16x8*)(wb + 48 * 1024);
        const f16x8 w6f1 = *(const f16x8*)(wb + 49 * 1024);
#pragma unroll
        for (int t = 0; t < TILES; ++t) {
            f32x4 z = {0.0f, 0.0f, 0.0f, 0.0f};
            z = MFMA32(w6f0, bf[t][0], z);
            z = MFMA32(w6f1, bf[t][1], z);
            // alpha+beta of sample t*16+m lives in lane t*16+m's registers
            const int src = t * 16 + m;
            const float s0 = __shfl(ab0, src);
            const float s1 = __shfl(ab1, src);
            const float s2 = __shfl(ab2, src);
            if (lane < 16) {   // q==0: D rows r=0..2 = output channels, col m
                const int s = wave_base + t * 16 + m;
                float* o = Out + s * 3;
                o[0] = z[0] * s0;
                o[1] = z[1] * s1;
                o[2] = z[2] * s2;
            }
        }
    }
}

extern "C" void kernel_launch(void* const* d_in, const int* in_sizes, int n_in,
                              void* d_out, int out_size, void* d_ws, size_t ws_size,
                              hipStream_t stream) {
    (void)n_in; (void)out_size;
    const float* P  = (const float*)d_in[0];
    const float* WI = (const float*)d_in[1];
    const float* NV = (const float*)d_in[2];
    const float* AL = (const float*)d_in[3];
    const float* BE = (const float*)d_in[4];
    const float* RR = (const float*)d_in[5];
    const float* W0 = (const float*)d_in[6];
    const float* W1 = (const float*)d_in[7];
    const float* W2 = (const float*)d_in[8];
    const float* W3 = (const float*)d_in[9];
    const float* W4 = (const float*)d_in[10];
    const float* W5 = (const float*)d_in[11];
    const float* W6 = (const float*)d_in[12];
    f16*   ws  = (f16*)d_ws;
    float* Out = (float*)d_out;

    const int Bn = in_sizes[0] / 3;     // 1,048,576
    const int grid = Bn / SPB;          // 2048 blocks of 512 threads

    // ws_size fixed per session -> same path every call (graph-safe).
    if (ws_size >= WS_BYTES) {
        hipLaunchKernelGGL(pack_weights_kernel, dim3((WCHUNKS + 255) / 256),
                           dim3(256), 0, stream, W0, W1, W2, W3, W4, W5, W6, ws);
        hipLaunchKernelGGL((nrc_mlp_kernel<1>), dim3(grid), dim3(BLOCK), 0, stream,
                           P, WI, NV, AL, BE, RR, ws,
                           W0, W1, W2, W3, W4, W5, W6, Out);
    } else {
        hipLaunchKernelGGL((nrc_mlp_kernel<0>), dim3(grid), dim3(BLOCK), 0, stream,
                           P, WI, NV, AL, BE, RR, ws,
                           W0, W1, W2, W3, W4, W5, W6, Out);
    }
}